// Round 1
// baseline (736.176 us; speedup 1.0000x reference)
//
#include <hip/hip_runtime.h>

// PatchEmbedding: unfold(k=2, stride=1, pad=0) on (1,3,384,384) fp32,
// linear 12->768, + bias + positions. out[e][l] with l = p*383+q.
//
// Memory-bound: ~451 MB positions read + ~451 MB out write dominate.
// x (1.77 MB) is L2-resident; W/b are wave-uniform scalar loads.

constexpr int IMG = 384;
constexpr int L1  = IMG - 1;        // 383
constexpr int L   = L1 * L1;        // 146689
constexpr int EMB = 768;
constexpr int PD  = 12;             // 3 * 2 * 2
constexpr int EPB = 16;             // embedding channels per block (grid.y)
constexpr int NG  = (L + 3) / 4;    // 36673 float4 groups along l

// e*L + l0 is only 4B-aligned (L odd) -> 16B access with 4B alignment.
// AMDGPU allows dword-aligned multi-dword vector memory ops.
struct __attribute__((packed, aligned(4))) f4u { float x, y, z, w; };

__global__ __launch_bounds__(256) void patch_embed_kernel(
    const float* __restrict__ x,
    const float* __restrict__ W,
    const float* __restrict__ b,
    const float* __restrict__ pos,
    float* __restrict__ out)
{
    const int g = blockIdx.x * blockDim.x + threadIdx.x;   // float4-group index
    if (g >= NG) return;
    const int l0    = g * 4;
    const int e0    = blockIdx.y * EPB;
    const int valid = min(4, L - l0);                      // 4 except last group (1)

    // Gather the 12 patch values for each of the 4 lanes. All hits in L1/L2
    // (x is 1.77 MB). d = c*4 + i*2 + j matches torch unfold channel order.
    float patch[4][PD];
    #pragma unroll
    for (int lane = 0; lane < 4; ++lane) {
        int l = l0 + lane;
        if (l >= L) l = L - 1;                             // clamp; unused lanes
        const unsigned p = (unsigned)l / L1;
        const unsigned q = (unsigned)l - p * L1;
        const float* xp = x + p * IMG + q;
        #pragma unroll
        for (int c = 0; c < 3; ++c)
            #pragma unroll
            for (int i = 0; i < 2; ++i)
                #pragma unroll
                for (int j = 0; j < 2; ++j)
                    patch[lane][c * 4 + i * 2 + j] = xp[c * IMG * IMG + i * IMG + j];
    }

    // Loop over 16 embedding channels; W/b indices are wave-uniform -> s_load.
    #pragma unroll 4
    for (int ii = 0; ii < EPB; ++ii) {
        const int e = e0 + ii;
        float wreg[PD];
        #pragma unroll
        for (int d = 0; d < PD; ++d) wreg[d] = W[e * PD + d];
        const float bias = b[e];
        const size_t base = (size_t)e * L + (size_t)l0;

        float r[4];
        #pragma unroll
        for (int lane = 0; lane < 4; ++lane) {
            float acc = bias;
            #pragma unroll
            for (int d = 0; d < PD; ++d)
                acc = fmaf(wreg[d], patch[lane][d], acc);
            r[lane] = acc;
        }

        if (valid == 4) {
            f4u p4 = *(const f4u*)(pos + base);
            f4u o;
            o.x = r[0] + p4.x;
            o.y = r[1] + p4.y;
            o.z = r[2] + p4.z;
            o.w = r[3] + p4.w;
            *(f4u*)(out + base) = o;
        } else {
            for (int lane = 0; lane < valid; ++lane)
                out[base + lane] = r[lane] + pos[base + lane];
        }
    }
}

extern "C" void kernel_launch(void* const* d_in, const int* in_sizes, int n_in,
                              void* d_out, int out_size, void* d_ws, size_t ws_size,
                              hipStream_t stream) {
    const float* x   = (const float*)d_in[0];
    const float* W   = (const float*)d_in[1];
    const float* b   = (const float*)d_in[2];
    const float* pos = (const float*)d_in[3];
    float* out = (float*)d_out;

    dim3 block(256);
    dim3 grid((NG + 255) / 256, EMB / EPB);   // 144 x 48 = 6912 blocks
    patch_embed_kernel<<<grid, block, 0, stream>>>(x, W, b, pos, out);
}